// Round 7
// baseline (57.502 us; speedup 1.0000x reference)
//
#include <hip/hip_runtime.h>

#define NBINS 10
#define C 10

constexpr int BLOCK = 256;
constexpr int GRIDH = 1024;                         // hist-role blocks (even blockIdx)
constexpr int GRIDA = 1024;                         // arg-role blocks (odd blockIdx)
constexpr int PSTR  = 32;                           // padded partial-row stride (floats)
constexpr int PAIRS_PER_TILE = BLOCK;               // 256 pairs = 512 samples / tile
constexpr int F4_PER_TILE    = PAIRS_PER_TILE * 5;  // 1280 float4

// d_ws float layout:
//   [0, GRIDH*PSTR)                 conf partials (cumulative S_t sums)
//   [GRIDH*PSTR, 2*GRIDH*PSTR)      cnt partials  (G_t counts, f32-exact < 2^24)
//   [2*GRIDH*PSTR, +GRIDA*PSTR)     cor partials
// Every slot read by ece_reduce is rewritten every call — no memset needed.

__global__ __launch_bounds__(BLOCK) void ece_fused(
    const float4* __restrict__ p4,
    const int2*   __restrict__ l2,
    float*        __restrict__ part,
    int npairs, int nf4)
{
    __shared__ float        s_stage[F4_PER_TILE * 4];   // 20 KB: arg staging / hist scratch
    __shared__ unsigned int s_cor[NBINS];

    const int tid  = threadIdx.x;
    const int lane = tid & 63, wave = tid >> 6;
    const int row  = blockIdx.x >> 1;

    const float EDGE[NBINS] = {
        (float)(0*0.1), (float)(1*0.1), (float)(2*0.1), (float)(3*0.1), (float)(4*0.1),
        (float)(5*0.1), (float)(6*0.1), (float)(7*0.1), (float)(8*0.1), (float)(9*0.1)};

    if ((blockIdx.x & 1) == 0) {
        // ========== hist role: coalesced stream, 4 VALU/edge, no SALU ladder ==========
        float        conf[NBINS];
        unsigned int cnt1[NBINS];          // cnt1[0] unused; edges 1..9
        unsigned int nf = 0;               // float4s processed -> cnt[0] = 4*nf
#pragma unroll
        for (int t = 0; t < NBINS; ++t) { conf[t] = 0.0f; cnt1[t] = 0u; }

        const int stride = GRIDH * BLOCK;
        int fi = row * BLOCK + tid;

#define PROC_F4(q)                                                          \
        {                                                                   \
            const float e_[4] = {(q).x, (q).y, (q).z, (q).w};               \
            conf[0] += ((q).x + (q).y) + ((q).z + (q).w);                   \
            _Pragma("unroll")                                               \
            for (int j_ = 0; j_ < 4; ++j_) {                                \
                const float x_ = e_[j_];                                    \
                _Pragma("unroll")                                           \
                for (int t_ = 1; t_ < NBINS; ++t_) {                        \
                    const bool g_ = x_ > EDGE[t_];                          \
                    cnt1[t_] += g_ ? 1u : 0u;   /* shares v_cmp */          \
                    conf[t_] += g_ ? x_ : 0.0f; /* cndmask + add */         \
                }                                                           \
            }                                                               \
        }

        for (; fi + stride < nf4; fi += 2 * stride) {
            const float4 qa = p4[fi];
            const float4 qb = p4[fi + stride];
            PROC_F4(qa);
            PROC_F4(qb);
            nf += 2;
        }
        if (fi < nf4) {
            const float4 qa = p4[fi];
            PROC_F4(qa);
            nf += 1;
        }
#undef PROC_F4

        unsigned int cnt0 = 4u * nf;       // x > 0 always (softmax, no underflow here)

        // 64-lane butterfly
#pragma unroll
        for (int t = 0; t < NBINS; ++t)
            for (int o = 32; o > 0; o >>= 1)
                conf[t] += __shfl_xor(conf[t], o, 64);
        for (int o = 32; o > 0; o >>= 1) cnt0 += __shfl_xor(cnt0, o, 64);
#pragma unroll
        for (int t = 1; t < NBINS; ++t)
            for (int o = 32; o > 0; o >>= 1)
                cnt1[t] += __shfl_xor(cnt1[t], o, 64);

        float* s_confr = s_stage;                  // [4][NBINS] scratch reuse
        float* s_cntr  = s_stage + 4 * NBINS;
        if (lane == 0) {
#pragma unroll
            for (int t = 0; t < NBINS; ++t) {
                s_confr[wave * NBINS + t] = conf[t];
                s_cntr [wave * NBINS + t] = (t == 0) ? (float)cnt0 : (float)cnt1[t];
            }
        }
        __syncthreads();

        if (tid < 12) {   // 12 slots (2 zero pads) so reduce can float4-load
            float fc = 0.0f, fn = 0.0f;
            if (tid < NBINS) {
#pragma unroll
                for (int w = 0; w < 4; ++w) {
                    fc += s_confr[w * NBINS + tid];
                    fn += s_cntr [w * NBINS + tid];
                }
            }
            part[(size_t)row * PSTR + tid]                = fc;
            part[(size_t)GRIDH * PSTR + row * PSTR + tid] = fn;
        }
    } else {
        // ========== arg role: LDS-staged; correct <=> p[label] == max ==========
        if (tid < NBINS) s_cor[tid] = 0u;

        float4* s4 = reinterpret_cast<float4*>(s_stage);
        const int ntiles = (npairs + PAIRS_PER_TILE - 1) / PAIRS_PER_TILE;

        for (int tile = row; tile < ntiles; tile += GRIDA) {
            __syncthreads();   // protect s_stage reuse (and s_cor init on first pass)

            const int f4base = tile * F4_PER_TILE;
#pragma unroll
            for (int k = 0; k < 5; ++k) {
                const int fi = f4base + k * BLOCK + tid;
                if (fi < nf4) s4[k * BLOCK + tid] = p4[fi];   // linear LDS write
            }
            __syncthreads();

            const int pr = tile * PAIRS_PER_TILE + tid;
            if (pr < npairs) {
                const int base = tid * 20;
                const float4* rw = reinterpret_cast<const float4*>(&s_stage[base]);
                const float4 q0 = rw[0], q1 = rw[1], q2 = rw[2], q3 = rw[3], q4 = rw[4];
                const int2 lab = l2[pr];

                // sample A: elems 0..9 — pure max chain (v_max3-friendly)
                const float mA = fmaxf(fmaxf(fmaxf(fmaxf(q0.x, q0.y), fmaxf(q0.z, q0.w)),
                                             fmaxf(fmaxf(q1.x, q1.y), fmaxf(q1.z, q1.w))),
                                       fmaxf(q2.x, q2.y));
                const float plA = s_stage[base + lab.x];       // runtime LDS gather
                if (plA >= mA) {                               // == max -> correct
                    const int im = min((int)ceilf(plA * 10.0f) - 1, NBINS - 1);
                    if (im >= 0) atomicAdd(&s_cor[im], 1u);    // LDS only, ~10% hit
                }

                // sample B: elems 10..19
                const float mB = fmaxf(fmaxf(fmaxf(fmaxf(q2.z, q2.w), fmaxf(q3.x, q3.y)),
                                             fmaxf(fmaxf(q3.z, q3.w), fmaxf(q4.x, q4.y))),
                                       fmaxf(q4.z, q4.w));
                const float plB = s_stage[base + 10 + lab.y];
                if (plB >= mB) {
                    const int im = min((int)ceilf(plB * 10.0f) - 1, NBINS - 1);
                    if (im >= 0) atomicAdd(&s_cor[im], 1u);
                }
            }
        }
        __syncthreads();

        if (tid < 12) {
            const float v = (tid < NBINS) ? (float)s_cor[tid] : 0.0f;
            part[(size_t)2 * GRIDH * PSTR + row * PSTR + tid] = v;
        }
    }
}

__global__ __launch_bounds__(256) void ece_reduce(
    const float* __restrict__ part,
    float* __restrict__ out)
{
    __shared__ double s_c[4][NBINS];
    __shared__ double s_n[4][NBINS];
    __shared__ double s_r[4][NBINS];

    const int tid = threadIdx.x;
    const int lane = tid & 63, wave = tid >> 6;

    double conf[NBINS], cntd[NBINS], cord[NBINS];
#pragma unroll
    for (int t = 0; t < NBINS; ++t) { conf[t] = 0.0; cntd[t] = 0.0; cord[t] = 0.0; }

    for (int b = tid; b < GRIDH; b += 256) {
        const float4* rc = reinterpret_cast<const float4*>(part + (size_t)b * PSTR);
        const float4* rn = reinterpret_cast<const float4*>(part + (size_t)GRIDH * PSTR + b * PSTR);
        const float4* rr = reinterpret_cast<const float4*>(part + (size_t)2 * GRIDH * PSTR + b * PSTR);
        const float4 c0 = rc[0], c1 = rc[1], c2 = rc[2];
        const float4 n0 = rn[0], n1 = rn[1], n2 = rn[2];
        const float4 r0 = rr[0], r1 = rr[1], r2 = rr[2];
        const float cf[12] = {c0.x,c0.y,c0.z,c0.w, c1.x,c1.y,c1.z,c1.w, c2.x,c2.y,c2.z,c2.w};
        const float nf[12] = {n0.x,n0.y,n0.z,n0.w, n1.x,n1.y,n1.z,n1.w, n2.x,n2.y,n2.z,n2.w};
        const float rf[12] = {r0.x,r0.y,r0.z,r0.w, r1.x,r1.y,r1.z,r1.w, r2.x,r2.y,r2.z,r2.w};
#pragma unroll
        for (int t = 0; t < NBINS; ++t) {
            conf[t] += (double)cf[t];
            cntd[t] += (double)nf[t];
            cord[t] += (double)rf[t];
        }
    }

#pragma unroll
    for (int t = 0; t < NBINS; ++t) {
        for (int o = 32; o > 0; o >>= 1) {
            conf[t] += __shfl_xor(conf[t], o, 64);
            cntd[t] += __shfl_xor(cntd[t], o, 64);
            cord[t] += __shfl_xor(cord[t], o, 64);
        }
    }
    if (lane == 0) {
#pragma unroll
        for (int t = 0; t < NBINS; ++t) {
            s_c[wave][t] = conf[t]; s_n[wave][t] = cntd[t]; s_r[wave][t] = cord[t];
        }
    }
    __syncthreads();

    if (tid == 0) {
        double S[NBINS + 1], G[NBINS + 1], R[NBINS];
        for (int t = 0; t < NBINS; ++t) {
            G[t] = s_n[0][t] + s_n[1][t] + s_n[2][t] + s_n[3][t];
            R[t] = s_r[0][t] + s_r[1][t] + s_r[2][t] + s_r[3][t];
            S[t] = s_c[0][t] + s_c[1][t] + s_c[2][t] + s_c[3][t];
        }
        S[NBINS] = 0.0; G[NBINS] = 0.0;

        double total = 0.0, ece = 0.0;
        for (int j = 0; j < NBINS; ++j) {
            const double c  = G[j] - G[j + 1];     // per-bin count
            const double sc = S[j] - S[j + 1];     // per-bin conf sum
            const double ba = R[j] / c;
            total += c;
            ece   += fabs(sc / c - ba) * c;
            out[1 + j]  = (float)((float)((j + 1) * 0.1) - 0.05f);  // centers
            out[11 + j] = (float)ba;
        }
        out[0] = (float)(ece / total);
    }
}

extern "C" void kernel_launch(void* const* d_in, const int* in_sizes, int n_in,
                              void* d_out, int out_size, void* d_ws, size_t ws_size,
                              hipStream_t stream)
{
    const float* probs  = (const float*)d_in[0];
    const int*   labels = (const int*)  d_in[1];
    float*       out    = (float*)d_out;
    const int n      = in_sizes[1];       // N_SAMPLES
    const int npairs = n / 2;
    const int nf4    = (n * C) / 4;

    float* part = (float*)d_ws;           // fully rewritten each call — no memset

    ece_fused<<<GRIDH + GRIDA, BLOCK, 0, stream>>>((const float4*)probs,
                                                   (const int2*)labels,
                                                   part, npairs, nf4);
    ece_reduce<<<1, 256, 0, stream>>>(part, out);
}

// Round 8
// 43.454 us; speedup vs baseline: 1.3233x; 1.3233x over previous
//
#include <hip/hip_runtime.h>

#define NBINS 10
#define C 10

constexpr int BLOCK = 256;
constexpr int GRIDH = 1536;   // hist-role blocks: blockIdx in [0, GRIDH)
constexpr int GRIDA = 512;    // arg-role blocks:  blockIdx in [GRIDH, GRIDH+GRIDA)
constexpr int PSTR  = 32;     // padded partial-row stride (floats)

// d_ws float layout:
//   [0, GRIDH*PSTR)                  conf partials (cumulative S_t sums)
//   [GRIDH*PSTR, 2*GRIDH*PSTR)       cnt partials  (G_t counts, f32-exact < 2^24)
//   [2*GRIDH*PSTR, +GRIDA*PSTR)      cor partials
// Every slot read by ece_reduce is rewritten every call — no memset needed.

__global__ __launch_bounds__(BLOCK) void ece_fused(
    const float4* __restrict__ p4,
    const int2*   __restrict__ l2,
    float*        __restrict__ part,
    int npairs, int nf4)
{
    __shared__ float        s_red[8 * NBINS];   // tiny cross-wave scratch
    __shared__ unsigned int s_cor[NBINS];

    const int tid  = threadIdx.x;
    const int lane = tid & 63, wave = tid >> 6;

    const float EDGE[NBINS] = {
        (float)(0*0.1), (float)(1*0.1), (float)(2*0.1), (float)(3*0.1), (float)(4*0.1),
        (float)(5*0.1), (float)(6*0.1), (float)(7*0.1), (float)(8*0.1), (float)(9*0.1)};

    if (blockIdx.x < GRIDH) {
        // ========== hist role: coalesced stream, 4 VALU/edge, no LDS, no barriers ==========
        const int row = blockIdx.x;
        float        conf[NBINS];
        unsigned int cnt1[NBINS];          // edges 1..9 ([0] unused)
        unsigned int nf = 0;               // float4s processed -> cnt[0] = 4*nf
#pragma unroll
        for (int t = 0; t < NBINS; ++t) { conf[t] = 0.0f; cnt1[t] = 0u; }

        const int stride = GRIDH * BLOCK;
        int fi = row * BLOCK + tid;

#define PROC_F4(q)                                                          \
        {                                                                   \
            const float e_[4] = {(q).x, (q).y, (q).z, (q).w};               \
            conf[0] += ((q).x + (q).y) + ((q).z + (q).w);                   \
            _Pragma("unroll")                                               \
            for (int j_ = 0; j_ < 4; ++j_) {                                \
                const float x_ = e_[j_];                                    \
                _Pragma("unroll")                                           \
                for (int t_ = 1; t_ < NBINS; ++t_) {                        \
                    const bool g_ = x_ > EDGE[t_];                          \
                    cnt1[t_] += g_ ? 1u : 0u;   /* shares v_cmp */          \
                    conf[t_] += g_ ? x_ : 0.0f; /* cndmask + add */         \
                }                                                           \
            }                                                               \
        }

        for (; fi + stride < nf4; fi += 2 * stride) {
            const float4 qa = p4[fi];
            const float4 qb = p4[fi + stride];
            PROC_F4(qa);
            PROC_F4(qb);
            nf += 2;
        }
        if (fi < nf4) {
            const float4 qa = p4[fi];
            PROC_F4(qa);
            nf += 1;
        }
#undef PROC_F4

        unsigned int cnt0 = 4u * nf;       // x > 0 always (softmax output)

        // 64-lane butterfly
#pragma unroll
        for (int t = 0; t < NBINS; ++t)
            for (int o = 32; o > 0; o >>= 1)
                conf[t] += __shfl_xor(conf[t], o, 64);
        for (int o = 32; o > 0; o >>= 1) cnt0 += __shfl_xor(cnt0, o, 64);
#pragma unroll
        for (int t = 1; t < NBINS; ++t)
            for (int o = 32; o > 0; o >>= 1)
                cnt1[t] += __shfl_xor(cnt1[t], o, 64);

        if (lane == 0) {
#pragma unroll
            for (int t = 0; t < NBINS; ++t) {
                s_red[wave * NBINS + t]             = conf[t];
                s_red[(4 + wave) * NBINS + t]       = (t == 0) ? (float)cnt0 : (float)cnt1[t];
            }
        }
        __syncthreads();

        if (tid < 12) {   // 12 slots (2 zero pads) so reduce can float4-load
            float fc = 0.0f, fn = 0.0f;
            if (tid < NBINS) {
#pragma unroll
                for (int w = 0; w < 4; ++w) {
                    fc += s_red[w * NBINS + tid];
                    fn += s_red[(4 + w) * NBINS + tid];
                }
            }
            part[(size_t)row * PSTR + tid]                = fc;
            part[(size_t)GRIDH * PSTR + row * PSTR + tid] = fn;
        }
    } else {
        // ========== arg role: direct reads, register label-select, no barriers in loop ==========
        const int row = blockIdx.x - GRIDH;
        if (tid < NBINS) s_cor[tid] = 0u;
        __syncthreads();

        const int stride = GRIDA * BLOCK;
        for (int pr = row * BLOCK + tid; pr < npairs; pr += stride) {
            const float4* rw = p4 + (size_t)pr * 5;   // 80 B contiguous per lane
            const float4 q0 = rw[0], q1 = rw[1], q2 = rw[2], q3 = rw[3], q4 = rw[4];
            const int2 lab = l2[pr];

            // ---- sample A: elems 0..9 ----
            const float mA = fmaxf(fmaxf(fmaxf(fmaxf(q0.x, q0.y), fmaxf(q0.z, q0.w)),
                                         fmaxf(fmaxf(q1.x, q1.y), fmaxf(q1.z, q1.w))),
                                   fmaxf(q2.x, q2.y));
            float plA = q0.x;                          // p[label] via cndmask chain
            plA = (lab.x == 1) ? q0.y : plA;
            plA = (lab.x == 2) ? q0.z : plA;
            plA = (lab.x == 3) ? q0.w : plA;
            plA = (lab.x == 4) ? q1.x : plA;
            plA = (lab.x == 5) ? q1.y : plA;
            plA = (lab.x == 6) ? q1.z : plA;
            plA = (lab.x == 7) ? q1.w : plA;
            plA = (lab.x == 8) ? q2.x : plA;
            plA = (lab.x == 9) ? q2.y : plA;
            if (plA >= mA) {                           // == max -> predicted correct
                const int im = min((int)ceilf(plA * 10.0f) - 1, NBINS - 1);
                if (im >= 0) atomicAdd(&s_cor[im], 1u);   // LDS only, ~10% hit rate
            }

            // ---- sample B: elems 10..19 ----
            const float mB = fmaxf(fmaxf(fmaxf(fmaxf(q2.z, q2.w), fmaxf(q3.x, q3.y)),
                                         fmaxf(fmaxf(q3.z, q3.w), fmaxf(q4.x, q4.y))),
                                   fmaxf(q4.z, q4.w));
            float plB = q2.z;
            plB = (lab.y == 1) ? q2.w : plB;
            plB = (lab.y == 2) ? q3.x : plB;
            plB = (lab.y == 3) ? q3.y : plB;
            plB = (lab.y == 4) ? q3.z : plB;
            plB = (lab.y == 5) ? q3.w : plB;
            plB = (lab.y == 6) ? q4.x : plB;
            plB = (lab.y == 7) ? q4.y : plB;
            plB = (lab.y == 8) ? q4.z : plB;
            plB = (lab.y == 9) ? q4.w : plB;
            if (plB >= mB) {
                const int im = min((int)ceilf(plB * 10.0f) - 1, NBINS - 1);
                if (im >= 0) atomicAdd(&s_cor[im], 1u);
            }
        }
        __syncthreads();

        if (tid < 12) {
            const float v = (tid < NBINS) ? (float)s_cor[tid] : 0.0f;
            part[(size_t)2 * GRIDH * PSTR + row * PSTR + tid] = v;
        }
    }
}

__global__ __launch_bounds__(256) void ece_reduce(
    const float* __restrict__ part,
    float* __restrict__ out)
{
    __shared__ double s_c[4][NBINS];
    __shared__ double s_n[4][NBINS];
    __shared__ double s_r[4][NBINS];

    const int tid = threadIdx.x;
    const int lane = tid & 63, wave = tid >> 6;

    double conf[NBINS], cntd[NBINS], cord[NBINS];
#pragma unroll
    for (int t = 0; t < NBINS; ++t) { conf[t] = 0.0; cntd[t] = 0.0; cord[t] = 0.0; }

    for (int b = tid; b < GRIDH; b += 256) {
        const float4* rc = reinterpret_cast<const float4*>(part + (size_t)b * PSTR);
        const float4* rn = reinterpret_cast<const float4*>(part + (size_t)GRIDH * PSTR + b * PSTR);
        const float4 c0 = rc[0], c1 = rc[1], c2 = rc[2];
        const float4 n0 = rn[0], n1 = rn[1], n2 = rn[2];
        const float cf[12] = {c0.x,c0.y,c0.z,c0.w, c1.x,c1.y,c1.z,c1.w, c2.x,c2.y,c2.z,c2.w};
        const float nf[12] = {n0.x,n0.y,n0.z,n0.w, n1.x,n1.y,n1.z,n1.w, n2.x,n2.y,n2.z,n2.w};
#pragma unroll
        for (int t = 0; t < NBINS; ++t) {
            conf[t] += (double)cf[t];
            cntd[t] += (double)nf[t];
        }
        if (b < GRIDA) {
            const float4* rr = reinterpret_cast<const float4*>(part + (size_t)2 * GRIDH * PSTR + b * PSTR);
            const float4 r0 = rr[0], r1 = rr[1], r2 = rr[2];
            const float rf[12] = {r0.x,r0.y,r0.z,r0.w, r1.x,r1.y,r1.z,r1.w, r2.x,r2.y,r2.z,r2.w};
#pragma unroll
            for (int t = 0; t < NBINS; ++t) cord[t] += (double)rf[t];
        }
    }

#pragma unroll
    for (int t = 0; t < NBINS; ++t) {
        for (int o = 32; o > 0; o >>= 1) {
            conf[t] += __shfl_xor(conf[t], o, 64);
            cntd[t] += __shfl_xor(cntd[t], o, 64);
            cord[t] += __shfl_xor(cord[t], o, 64);
        }
    }
    if (lane == 0) {
#pragma unroll
        for (int t = 0; t < NBINS; ++t) {
            s_c[wave][t] = conf[t]; s_n[wave][t] = cntd[t]; s_r[wave][t] = cord[t];
        }
    }
    __syncthreads();

    if (tid == 0) {
        double S[NBINS + 1], G[NBINS + 1], R[NBINS];
        for (int t = 0; t < NBINS; ++t) {
            G[t] = s_n[0][t] + s_n[1][t] + s_n[2][t] + s_n[3][t];
            R[t] = s_r[0][t] + s_r[1][t] + s_r[2][t] + s_r[3][t];
            S[t] = s_c[0][t] + s_c[1][t] + s_c[2][t] + s_c[3][t];
        }
        S[NBINS] = 0.0; G[NBINS] = 0.0;

        double total = 0.0, ece = 0.0;
        for (int j = 0; j < NBINS; ++j) {
            const double c  = G[j] - G[j + 1];     // per-bin count
            const double sc = S[j] - S[j + 1];     // per-bin conf sum
            const double ba = R[j] / c;
            total += c;
            ece   += fabs(sc / c - ba) * c;
            out[1 + j]  = (float)((float)((j + 1) * 0.1) - 0.05f);  // centers
            out[11 + j] = (float)ba;
        }
        out[0] = (float)(ece / total);
    }
}

extern "C" void kernel_launch(void* const* d_in, const int* in_sizes, int n_in,
                              void* d_out, int out_size, void* d_ws, size_t ws_size,
                              hipStream_t stream)
{
    const float* probs  = (const float*)d_in[0];
    const int*   labels = (const int*)  d_in[1];
    float*       out    = (float*)d_out;
    const int n      = in_sizes[1];       // N_SAMPLES
    const int npairs = n / 2;
    const int nf4    = (n * C) / 4;

    float* part = (float*)d_ws;           // fully rewritten each call — no memset

    ece_fused<<<GRIDH + GRIDA, BLOCK, 0, stream>>>((const float4*)probs,
                                                   (const int2*)labels,
                                                   part, npairs, nf4);
    ece_reduce<<<1, 256, 0, stream>>>(part, out);
}